// Round 1
// baseline (1277.421 us; speedup 1.0000x reference)
//
#include <hip/hip_runtime.h>

#define NN 40000
#define EE 640000
#define KDIN 128
#define KDOUT 256

// ---------------------------------------------------------------- elementwise
__global__ __launch_bounds__(256) void k_init_h(const float4* __restrict__ x,
                                                const float* __restrict__ eps,
                                                float4* __restrict__ h) {
    int i = blockIdx.x * 256 + threadIdx.x;
    const int n4 = NN * KDIN / 4;
    if (i < n4) {
        float s = 1.0f + eps[0];
        float4 v = x[i];
        v.x *= s; v.y *= s; v.z *= s; v.w *= s;
        h[i] = v;
    }
}

// ------------------------------------------------------------------- scatter
// One 32-lane group per edge: lane c handles float4 c of the 128-dim row.
__global__ __launch_bounds__(256) void k_scatter(const float4* __restrict__ x4,
                                                 const int* __restrict__ ei,
                                                 float* __restrict__ h) {
    int gid = blockIdx.x * 256 + threadIdx.x;
    int e = gid >> 5;
    int c = gid & 31;
    if (e >= EE) return;
    int src = ei[e];
    int dst = ei[EE + e];
    float4 v = x4[(size_t)src * 32 + c];
    float* p = h + (size_t)dst * KDIN + c * 4;
    atomicAdd(p + 0, v.x);
    atomicAdd(p + 1, v.y);
    atomicAdd(p + 2, v.z);
    atomicAdd(p + 3, v.w);
}

// --------------------------------------------------------------- fp32 GEMMs
// 64x64 output tile, BK=32, 256 threads, 4x4 micro-tile per thread.
// A: [M x K] row-major, W: [K x 256] row-major.

#define TILE_LOAD(A_, W_, K_, k0_)                                              \
    {                                                                           \
        int ar = tid >> 2, ac = tid & 3;                                        \
        const float4* Ag = (const float4*)(A_ + (size_t)(bm * 64 + ar) * (K_) + (k0_)); \
        float4 a0 = Ag[ac];                                                     \
        float4 a1 = Ag[ac + 4];                                                 \
        As[ac * 4 + 0][ar] = a0.x; As[ac * 4 + 1][ar] = a0.y;                   \
        As[ac * 4 + 2][ar] = a0.z; As[ac * 4 + 3][ar] = a0.w;                   \
        As[ac * 4 + 16][ar] = a1.x; As[ac * 4 + 17][ar] = a1.y;                 \
        As[ac * 4 + 18][ar] = a1.z; As[ac * 4 + 19][ar] = a1.w;                 \
        int br = tid >> 3, bc = tid & 7;                                        \
        const float4* Wg = (const float4*)(W_ + (size_t)((k0_) + br) * KDOUT + bn * 64); \
        ((float4*)Bs[br])[bc] = Wg[bc];                                         \
        ((float4*)Bs[br])[bc + 8] = Wg[bc + 8];                                 \
    }

#define TILE_FMA(acc_)                                                          \
    _Pragma("unroll")                                                           \
    for (int kk = 0; kk < 32; ++kk) {                                           \
        float a0 = As[kk][ty * 4 + 0], a1 = As[kk][ty * 4 + 1];                 \
        float a2 = As[kk][ty * 4 + 2], a3 = As[kk][ty * 4 + 3];                 \
        float4 b = ((float4*)Bs[kk])[tx];                                       \
        acc_[0][0] += a0 * b.x; acc_[0][1] += a0 * b.y;                         \
        acc_[0][2] += a0 * b.z; acc_[0][3] += a0 * b.w;                         \
        acc_[1][0] += a1 * b.x; acc_[1][1] += a1 * b.y;                         \
        acc_[1][2] += a1 * b.z; acc_[1][3] += a1 * b.w;                         \
        acc_[2][0] += a2 * b.x; acc_[2][1] += a2 * b.y;                         \
        acc_[2][2] += a2 * b.z; acc_[2][3] += a2 * b.w;                         \
        acc_[3][0] += a3 * b.x; acc_[3][1] += a3 * b.y;                         \
        acc_[3][2] += a3 * b.z; acc_[3][3] += a3 * b.w;                         \
    }

// GEMM1: h1 = relu(bn1(h @ W1 + b1))
__global__ __launch_bounds__(256) void k_gemm1(
    const float* __restrict__ A, const float* __restrict__ W,
    const float* __restrict__ bb, const float* __restrict__ g,
    const float* __restrict__ bt, const float* __restrict__ m,
    const float* __restrict__ vv, float* __restrict__ C) {
    __shared__ float As[32][65];
    __shared__ float Bs[32][64];
    int bm = blockIdx.x >> 2, bn = blockIdx.x & 3;
    int tid = threadIdx.x;
    int tx = tid & 15, ty = tid >> 4;
    float acc[4][4] = {};
    for (int k0 = 0; k0 < KDIN; k0 += 32) {
        TILE_LOAD(A, W, KDIN, k0);
        __syncthreads();
        TILE_FMA(acc);
        __syncthreads();
    }
    int col0 = bn * 64 + tx * 4;
    float s[4], bo[4];
#pragma unroll
    for (int j = 0; j < 4; ++j) {
        s[j] = g[col0 + j] * rsqrtf(vv[col0 + j] + 1e-5f);
        bo[j] = (bb[col0 + j] - m[col0 + j]) * s[j] + bt[col0 + j];
    }
#pragma unroll
    for (int i = 0; i < 4; ++i) {
        int row = bm * 64 + ty * 4 + i;
        float4 o;
        o.x = fmaxf(acc[i][0] * s[0] + bo[0], 0.f);
        o.y = fmaxf(acc[i][1] * s[1] + bo[1], 0.f);
        o.z = fmaxf(acc[i][2] * s[2] + bo[2], 0.f);
        o.w = fmaxf(acc[i][3] * s[3] + bo[3], 0.f);
        *(float4*)(C + (size_t)row * KDOUT + col0) = o;
    }
}

// GEMM2 fused: out = relu( relu(bn2(h1 @ W2 + b2)) + x @ Wres )
__global__ __launch_bounds__(256) void k_gemm2(
    const float* __restrict__ H1, const float* __restrict__ W2,
    const float* __restrict__ bb, const float* __restrict__ g,
    const float* __restrict__ bt, const float* __restrict__ m,
    const float* __restrict__ vv,
    const float* __restrict__ X, const float* __restrict__ Wres,
    float* __restrict__ OUT) {
    __shared__ float As[32][65];
    __shared__ float Bs[32][64];
    int bm = blockIdx.x >> 2, bn = blockIdx.x & 3;
    int tid = threadIdx.x;
    int tx = tid & 15, ty = tid >> 4;
    float acc[4][4] = {};
    for (int k0 = 0; k0 < KDOUT; k0 += 32) {   // phase 1: h1 @ W2, K=256
        TILE_LOAD(H1, W2, KDOUT, k0);
        __syncthreads();
        TILE_FMA(acc);
        __syncthreads();
    }
    int col0 = bn * 64 + tx * 4;
    float t[4][4];
    {
        float s[4], bo[4];
#pragma unroll
        for (int j = 0; j < 4; ++j) {
            s[j] = g[col0 + j] * rsqrtf(vv[col0 + j] + 1e-5f);
            bo[j] = (bb[col0 + j] - m[col0 + j]) * s[j] + bt[col0 + j];
        }
#pragma unroll
        for (int i = 0; i < 4; ++i)
#pragma unroll
            for (int j = 0; j < 4; ++j)
                t[i][j] = fmaxf(acc[i][j] * s[j] + bo[j], 0.f);
    }
    float acc2[4][4] = {};
    for (int k0 = 0; k0 < KDIN; k0 += 32) {    // phase 2: x @ Wres, K=128
        TILE_LOAD(X, Wres, KDIN, k0);
        __syncthreads();
        TILE_FMA(acc2);
        __syncthreads();
    }
#pragma unroll
    for (int i = 0; i < 4; ++i) {
        int row = bm * 64 + ty * 4 + i;
        float4 o;
        o.x = fmaxf(t[i][0] + acc2[i][0], 0.f);
        o.y = fmaxf(t[i][1] + acc2[i][1], 0.f);
        o.z = fmaxf(t[i][2] + acc2[i][2], 0.f);
        o.w = fmaxf(t[i][3] + acc2[i][3], 0.f);
        *(float4*)(OUT + (size_t)row * KDOUT + col0) = o;
    }
}

// ------------------------------------------------------------------- launch
extern "C" void kernel_launch(void* const* d_in, const int* in_sizes, int n_in,
                              void* d_out, int out_size, void* d_ws, size_t ws_size,
                              hipStream_t stream) {
    const float* x    = (const float*)d_in[0];
    const int*   ei   = (const int*)d_in[1];
    const float* eps  = (const float*)d_in[2];
    const float* W1   = (const float*)d_in[3];
    const float* b1   = (const float*)d_in[4];
    const float* g1   = (const float*)d_in[5];
    const float* bt1  = (const float*)d_in[6];
    const float* m1   = (const float*)d_in[7];
    const float* v1   = (const float*)d_in[8];
    const float* W2   = (const float*)d_in[9];
    const float* b2   = (const float*)d_in[10];
    const float* g2   = (const float*)d_in[11];
    const float* bt2  = (const float*)d_in[12];
    const float* m2   = (const float*)d_in[13];
    const float* v2   = (const float*)d_in[14];
    const float* Wres = (const float*)d_in[15];
    float* out = (float*)d_out;

    float* h  = (float*)d_ws;                         // [NN, 128]
    float* h1 = h + (size_t)NN * KDIN;                // [NN, 256]

    // h = (1+eps)*x
    k_init_h<<<(NN * KDIN / 4 + 255) / 256, 256, 0, stream>>>(
        (const float4*)x, eps, (float4*)h);
    // h += scatter_add(x[src] -> dst)
    k_scatter<<<(EE * 32) / 256, 256, 0, stream>>>((const float4*)x, ei, h);
    // h1 = relu(bn1(h @ W1 + b1))
    k_gemm1<<<625 * 4, 256, 0, stream>>>(h, W1, b1, g1, bt1, m1, v1, h1);
    // out = relu(relu(bn2(h1 @ W2 + b2)) + x @ Wres)
    k_gemm2<<<625 * 4, 256, 0, stream>>>(h1, W2, b2, g2, bt2, m2, v2, x, Wres, out);
}

// Round 2
// 376.872 us; speedup vs baseline: 3.3895x; 3.3895x over previous
//
#include <hip/hip_runtime.h>

#define NN 40000
#define EE 640000
#define KDIN 128
#define KDOUT 256

// ------------------------------------------------------------- CSR build
__global__ __launch_bounds__(256) void k_hist(const int* __restrict__ ei,
                                              int* __restrict__ deg) {
    int e = blockIdx.x * 256 + threadIdx.x;
    if (e < EE) atomicAdd(&deg[ei[EE + e]], 1);
}

// single-block exclusive scan of deg[NN] -> starts[NN]
__global__ __launch_bounds__(1024) void k_scan(const int* __restrict__ deg,
                                               int* __restrict__ starts) {
    __shared__ int sdata[1024];
    __shared__ int carry;
    int t = threadIdx.x;
    if (t == 0) carry = 0;
    __syncthreads();
    for (int base = 0; base < NN; base += 1024) {
        int i = base + t;
        int v = (i < NN) ? deg[i] : 0;
        sdata[t] = v;
        __syncthreads();
#pragma unroll
        for (int off = 1; off < 1024; off <<= 1) {
            int add = (t >= off) ? sdata[t - off] : 0;
            __syncthreads();
            sdata[t] += add;
            __syncthreads();
        }
        int incl = sdata[t];
        if (i < NN) starts[i] = incl - v + carry;
        __syncthreads();
        if (t == 1023) carry += incl;
        __syncthreads();
    }
}

// fill csr_src; afterwards starts[i] == end_i (== start_{i+1})
__global__ __launch_bounds__(256) void k_fill(const int* __restrict__ ei,
                                              int* __restrict__ starts,
                                              int* __restrict__ csr_src) {
    int e = blockIdx.x * 256 + threadIdx.x;
    if (e >= EE) return;
    int src = ei[e];
    int dst = ei[EE + e];
    int pos = atomicAdd(&starts[dst], 1);
    csr_src[pos] = src;
}

// ---------------------------------------------------------------- gather
// 32 lanes per node (one float4 per lane). h = (1+eps)*x + sum_{src} x[src]
__global__ __launch_bounds__(256) void k_gather(const float4* __restrict__ x4,
                                                const int* __restrict__ ends,
                                                const int* __restrict__ csr_src,
                                                const float* __restrict__ eps,
                                                float4* __restrict__ h) {
    int gid = blockIdx.x * 256 + threadIdx.x;
    int node = gid >> 5;
    int lane = gid & 31;
    if (node >= NN) return;
    int start = (node == 0) ? 0 : ends[node - 1];
    int end = ends[node];
    float s = 1.0f + eps[0];
    float4 me = x4[(size_t)node * 32 + lane];
    float4 acc;
    acc.x = me.x * s; acc.y = me.y * s; acc.z = me.z * s; acc.w = me.w * s;
    for (int j = start; j < end; ++j) {
        int src = csr_src[j];
        float4 v = x4[(size_t)src * 32 + lane];
        acc.x += v.x; acc.y += v.y; acc.z += v.z; acc.w += v.w;
    }
    h[(size_t)node * 32 + lane] = acc;
}

// --------------------------------------------------------------- fp32 GEMMs
// 64x64 output tile, BK=32, 256 threads, 4x4 micro-tile per thread.

#define TILE_LOAD(A_, W_, K_, k0_)                                              \
    {                                                                           \
        int ar = tid >> 2, ac = tid & 3;                                        \
        const float4* Ag = (const float4*)(A_ + (size_t)(bm * 64 + ar) * (K_) + (k0_)); \
        float4 a0 = Ag[ac];                                                     \
        float4 a1 = Ag[ac + 4];                                                 \
        As[ac * 4 + 0][ar] = a0.x; As[ac * 4 + 1][ar] = a0.y;                   \
        As[ac * 4 + 2][ar] = a0.z; As[ac * 4 + 3][ar] = a0.w;                   \
        As[ac * 4 + 16][ar] = a1.x; As[ac * 4 + 17][ar] = a1.y;                 \
        As[ac * 4 + 18][ar] = a1.z; As[ac * 4 + 19][ar] = a1.w;                 \
        int br = tid >> 3, bc = tid & 7;                                        \
        const float4* Wg = (const float4*)(W_ + (size_t)((k0_) + br) * KDOUT + bn * 64); \
        ((float4*)Bs[br])[bc] = Wg[bc];                                         \
        ((float4*)Bs[br])[bc + 8] = Wg[bc + 8];                                 \
    }

#define TILE_FMA(acc_)                                                          \
    _Pragma("unroll")                                                           \
    for (int kk = 0; kk < 32; ++kk) {                                           \
        float a0 = As[kk][ty * 4 + 0], a1 = As[kk][ty * 4 + 1];                 \
        float a2 = As[kk][ty * 4 + 2], a3 = As[kk][ty * 4 + 3];                 \
        float4 b = ((float4*)Bs[kk])[tx];                                       \
        acc_[0][0] += a0 * b.x; acc_[0][1] += a0 * b.y;                         \
        acc_[0][2] += a0 * b.z; acc_[0][3] += a0 * b.w;                         \
        acc_[1][0] += a1 * b.x; acc_[1][1] += a1 * b.y;                         \
        acc_[1][2] += a1 * b.z; acc_[1][3] += a1 * b.w;                         \
        acc_[2][0] += a2 * b.x; acc_[2][1] += a2 * b.y;                         \
        acc_[2][2] += a2 * b.z; acc_[2][3] += a2 * b.w;                         \
        acc_[3][0] += a3 * b.x; acc_[3][1] += a3 * b.y;                         \
        acc_[3][2] += a3 * b.z; acc_[3][3] += a3 * b.w;                         \
    }

// GEMM1: h1 = relu(bn1(h @ W1 + b1))
__global__ __launch_bounds__(256) void k_gemm1(
    const float* __restrict__ A, const float* __restrict__ W,
    const float* __restrict__ bb, const float* __restrict__ g,
    const float* __restrict__ bt, const float* __restrict__ m,
    const float* __restrict__ vv, float* __restrict__ C) {
    __shared__ float As[32][65];
    __shared__ float Bs[32][64];
    int bm = blockIdx.x >> 2, bn = blockIdx.x & 3;
    int tid = threadIdx.x;
    int tx = tid & 15, ty = tid >> 4;
    float acc[4][4] = {};
    for (int k0 = 0; k0 < KDIN; k0 += 32) {
        TILE_LOAD(A, W, KDIN, k0);
        __syncthreads();
        TILE_FMA(acc);
        __syncthreads();
    }
    int col0 = bn * 64 + tx * 4;
    float s[4], bo[4];
#pragma unroll
    for (int j = 0; j < 4; ++j) {
        s[j] = g[col0 + j] * rsqrtf(vv[col0 + j] + 1e-5f);
        bo[j] = (bb[col0 + j] - m[col0 + j]) * s[j] + bt[col0 + j];
    }
#pragma unroll
    for (int i = 0; i < 4; ++i) {
        int row = bm * 64 + ty * 4 + i;
        float4 o;
        o.x = fmaxf(acc[i][0] * s[0] + bo[0], 0.f);
        o.y = fmaxf(acc[i][1] * s[1] + bo[1], 0.f);
        o.z = fmaxf(acc[i][2] * s[2] + bo[2], 0.f);
        o.w = fmaxf(acc[i][3] * s[3] + bo[3], 0.f);
        *(float4*)(C + (size_t)row * KDOUT + col0) = o;
    }
}

// GEMM2 fused: out = relu( relu(bn2(h1 @ W2 + b2)) + x @ Wres )
__global__ __launch_bounds__(256) void k_gemm2(
    const float* __restrict__ H1, const float* __restrict__ W2,
    const float* __restrict__ bb, const float* __restrict__ g,
    const float* __restrict__ bt, const float* __restrict__ m,
    const float* __restrict__ vv,
    const float* __restrict__ X, const float* __restrict__ Wres,
    float* __restrict__ OUT) {
    __shared__ float As[32][65];
    __shared__ float Bs[32][64];
    int bm = blockIdx.x >> 2, bn = blockIdx.x & 3;
    int tid = threadIdx.x;
    int tx = tid & 15, ty = tid >> 4;
    float acc[4][4] = {};
    for (int k0 = 0; k0 < KDOUT; k0 += 32) {   // phase 1: h1 @ W2, K=256
        TILE_LOAD(H1, W2, KDOUT, k0);
        __syncthreads();
        TILE_FMA(acc);
        __syncthreads();
    }
    int col0 = bn * 64 + tx * 4;
    float t[4][4];
    {
        float s[4], bo[4];
#pragma unroll
        for (int j = 0; j < 4; ++j) {
            s[j] = g[col0 + j] * rsqrtf(vv[col0 + j] + 1e-5f);
            bo[j] = (bb[col0 + j] - m[col0 + j]) * s[j] + bt[col0 + j];
        }
#pragma unroll
        for (int i = 0; i < 4; ++i)
#pragma unroll
            for (int j = 0; j < 4; ++j)
                t[i][j] = fmaxf(acc[i][j] * s[j] + bo[j], 0.f);
    }
    float acc2[4][4] = {};
    for (int k0 = 0; k0 < KDIN; k0 += 32) {    // phase 2: x @ Wres, K=128
        TILE_LOAD(X, Wres, KDIN, k0);
        __syncthreads();
        TILE_FMA(acc2);
        __syncthreads();
    }
#pragma unroll
    for (int i = 0; i < 4; ++i) {
        int row = bm * 64 + ty * 4 + i;
        float4 o;
        o.x = fmaxf(t[i][0] + acc2[i][0], 0.f);
        o.y = fmaxf(t[i][1] + acc2[i][1], 0.f);
        o.z = fmaxf(t[i][2] + acc2[i][2], 0.f);
        o.w = fmaxf(t[i][3] + acc2[i][3], 0.f);
        *(float4*)(OUT + (size_t)row * KDOUT + col0) = o;
    }
}

// ------------------------------------------------------------------- launch
extern "C" void kernel_launch(void* const* d_in, const int* in_sizes, int n_in,
                              void* d_out, int out_size, void* d_ws, size_t ws_size,
                              hipStream_t stream) {
    const float* x    = (const float*)d_in[0];
    const int*   ei   = (const int*)d_in[1];
    const float* eps  = (const float*)d_in[2];
    const float* W1   = (const float*)d_in[3];
    const float* b1   = (const float*)d_in[4];
    const float* g1   = (const float*)d_in[5];
    const float* bt1  = (const float*)d_in[6];
    const float* m1   = (const float*)d_in[7];
    const float* v1   = (const float*)d_in[8];
    const float* W2   = (const float*)d_in[9];
    const float* b2   = (const float*)d_in[10];
    const float* g2   = (const float*)d_in[11];
    const float* bt2  = (const float*)d_in[12];
    const float* m2   = (const float*)d_in[13];
    const float* v2   = (const float*)d_in[14];
    const float* Wres = (const float*)d_in[15];
    float* out = (float*)d_out;

    // Workspace layout (61.44 MB, same footprint as round 1):
    //   h  [NN,128] fp32
    //   h1 [NN,256] fp32  — its first 2.88 MB doubles as CSR scratch, which
    //                       is dead before k_gemm1 writes h1 (stream-ordered)
    float* h  = (float*)d_ws;
    float* h1 = h + (size_t)NN * KDIN;
    int* deg     = (int*)h1;        // [NN]
    int* starts  = deg + NN;        // [NN]
    int* csr_src = starts + NN;     // [EE]

    hipMemsetAsync(deg, 0, NN * sizeof(int), stream);
    k_hist<<<(EE + 255) / 256, 256, 0, stream>>>(ei, deg);
    k_scan<<<1, 1024, 0, stream>>>(deg, starts);
    k_fill<<<(EE + 255) / 256, 256, 0, stream>>>(ei, starts, csr_src);
    // h = (1+eps)*x + gather-sum ; starts[] now holds bucket ENDs
    k_gather<<<(NN * 32 + 255) / 256, 256, 0, stream>>>(
        (const float4*)x, starts, csr_src, eps, (float4*)h);
    // h1 = relu(bn1(h @ W1 + b1))
    k_gemm1<<<625 * 4, 256, 0, stream>>>(h, W1, b1, g1, bt1, m1, v1, h1);
    // out = relu(relu(bn2(h1 @ W2 + b2)) + x @ Wres)
    k_gemm2<<<625 * 4, 256, 0, stream>>>(h1, W2, b2, g2, bt2, m2, v2, x, Wres, out);
}

// Round 3
// 201.179 us; speedup vs baseline: 6.3497x; 1.8733x over previous
//
#include <hip/hip_runtime.h>

#define NN 40000
#define NPAD 40064          // 313 * 128
#define EE 640000
#define KDIN 128
#define KDOUT 256

typedef __attribute__((ext_vector_type(8))) short bf16x8;   // 8 bf16 = 4 VGPR
typedef __attribute__((ext_vector_type(4))) float f32x4;    // MFMA acc

static __device__ __forceinline__ unsigned short f2bf(float f) {
    union { float f; unsigned int u; } v; v.f = f;
    unsigned int r = (v.u + 0x7FFFu + ((v.u >> 16) & 1u)) >> 16;  // RNE
    return (unsigned short)r;
}
static __device__ __forceinline__ float bf2f(unsigned short h) {
    union { unsigned int u; float f; } v; v.u = ((unsigned int)h) << 16;
    return v.f;
}

// ------------------------------------------------------------- x -> bf16
__global__ __launch_bounds__(256) void k_cvt(const float4* __restrict__ x,
                                             ushort* __restrict__ xb) {
    int i = blockIdx.x * 256 + threadIdx.x;          // one 8-elem group
    if (i >= NN * KDIN / 8) return;
    float4 a = x[i * 2], b = x[i * 2 + 1];
    uint4 o;
    o.x = (unsigned)f2bf(a.x) | ((unsigned)f2bf(a.y) << 16);
    o.y = (unsigned)f2bf(a.z) | ((unsigned)f2bf(a.w) << 16);
    o.z = (unsigned)f2bf(b.x) | ((unsigned)f2bf(b.y) << 16);
    o.w = (unsigned)f2bf(b.z) | ((unsigned)f2bf(b.w) << 16);
    *(uint4*)(xb + (size_t)i * 8) = o;
}

// ---------------------------------------------- W [R][C] -> W^T bf16 [C][R]
__global__ __launch_bounds__(256) void k_wt(const float* __restrict__ w,
                                            ushort* __restrict__ wt,
                                            int R, int C) {
    int i = blockIdx.x * 256 + threadIdx.x;          // i = c*R + r
    if (i >= R * C) return;
    int c = i / R, r = i % R;
    wt[i] = f2bf(w[r * C + c]);
}

// ------------------------------------------------------------- CSR build
__global__ __launch_bounds__(256) void k_hist(const int* __restrict__ ei,
                                              int* __restrict__ deg) {
    int e = blockIdx.x * 256 + threadIdx.x;
    if (e < EE) atomicAdd(&deg[ei[EE + e]], 1);
}

__global__ __launch_bounds__(1024) void k_scan(const int* __restrict__ deg,
                                               int* __restrict__ starts) {
    __shared__ int wsum[16];
    __shared__ int carry;
    int t = threadIdx.x, lane = t & 63, wid = t >> 6;
    if (t == 0) carry = 0;
    __syncthreads();
    for (int base = 0; base < NN; base += 1024) {
        int i = base + t;
        int v = (i < NN) ? deg[i] : 0;
        int incl = v;
#pragma unroll
        for (int off = 1; off < 64; off <<= 1) {
            int u = __shfl_up(incl, off, 64);
            if (lane >= off) incl += u;
        }
        if (lane == 63) wsum[wid] = incl;
        __syncthreads();
        if (wid == 0 && lane < 16) {
            int s = wsum[lane];
            int si = s;
#pragma unroll
            for (int off = 1; off < 16; off <<= 1) {
                int u = __shfl_up(si, off, 64);
                if (lane >= off) si += u;
            }
            wsum[lane] = si - s;                     // exclusive wave offset
        }
        __syncthreads();
        if (i < NN) starts[i] = carry + wsum[wid] + incl - v;
        __syncthreads();                             // all carry reads done
        if (t == 1023) carry += wsum[15] + incl;     // chunk total
    }
}

// fill csr_src; afterwards starts[i] == end_i
__global__ __launch_bounds__(256) void k_fill(const int* __restrict__ ei,
                                              int* __restrict__ starts,
                                              int* __restrict__ csr_src) {
    int e = blockIdx.x * 256 + threadIdx.x;
    if (e >= EE) return;
    int src = ei[e];
    int dst = ei[EE + e];
    int pos = atomicAdd(&starts[dst], 1);
    csr_src[pos] = src;
}

// ---------------------------------------------------------------- gather
// 16 lanes per node, 8 bf16 per lane. h = (1+eps)*x + sum_{src} x[src]
__global__ __launch_bounds__(256) void k_gather(const ushort* __restrict__ xb,
                                                const int* __restrict__ ends,
                                                const int* __restrict__ csr_src,
                                                const float* __restrict__ eps,
                                                ushort* __restrict__ hb) {
    int gid = blockIdx.x * 256 + threadIdx.x;
    int node = gid >> 4, lane = gid & 15;
    if (node >= NN) return;
    int start = node ? ends[node - 1] : 0;
    int end = ends[node];
    float s = 1.0f + eps[0];
    float acc[8];
    {
        uint4 me = *(const uint4*)(xb + (size_t)node * KDIN + lane * 8);
        acc[0] = bf2f((unsigned short)(me.x & 0xffff)) * s;
        acc[1] = bf2f((unsigned short)(me.x >> 16)) * s;
        acc[2] = bf2f((unsigned short)(me.y & 0xffff)) * s;
        acc[3] = bf2f((unsigned short)(me.y >> 16)) * s;
        acc[4] = bf2f((unsigned short)(me.z & 0xffff)) * s;
        acc[5] = bf2f((unsigned short)(me.z >> 16)) * s;
        acc[6] = bf2f((unsigned short)(me.w & 0xffff)) * s;
        acc[7] = bf2f((unsigned short)(me.w >> 16)) * s;
    }
    for (int e = start; e < end; ++e) {
        int src = csr_src[e];
        uint4 v = *(const uint4*)(xb + (size_t)src * KDIN + lane * 8);
        acc[0] += bf2f((unsigned short)(v.x & 0xffff));
        acc[1] += bf2f((unsigned short)(v.x >> 16));
        acc[2] += bf2f((unsigned short)(v.y & 0xffff));
        acc[3] += bf2f((unsigned short)(v.y >> 16));
        acc[4] += bf2f((unsigned short)(v.z & 0xffff));
        acc[5] += bf2f((unsigned short)(v.z >> 16));
        acc[6] += bf2f((unsigned short)(v.w & 0xffff));
        acc[7] += bf2f((unsigned short)(v.w >> 16));
    }
    uint4 o;
    o.x = (unsigned)f2bf(acc[0]) | ((unsigned)f2bf(acc[1]) << 16);
    o.y = (unsigned)f2bf(acc[2]) | ((unsigned)f2bf(acc[3]) << 16);
    o.z = (unsigned)f2bf(acc[4]) | ((unsigned)f2bf(acc[5]) << 16);
    o.w = (unsigned)f2bf(acc[6]) | ((unsigned)f2bf(acc[7]) << 16);
    *(uint4*)(hb + (size_t)node * KDIN + lane * 8) = o;
}

// ------------------------------------------------------------ MFMA GEMMs
// Block: 256 threads = 4 waves. Tile BM=128 x BN=128. Wave w: rows w*32..+31.
// W^T column slice staged in LDS, XOR-swizzled: byte ^= (col&7)<<4.
// A-fragments loaded directly from global (L3-resident, read once per block).

#define STAGE_WT(Wt_, Kc_, K2_)                                                 \
    for (int id = tid; id < BNT * (K2_) / 16; id += 256) {                      \
        int c = id / ((K2_) / 16);                                              \
        int koff = (id % ((K2_) / 16)) * 16;                                    \
        uint4 v = *(const uint4*)((const char*)((Wt_) + (size_t)(ncol0 + c) * (Kc_)) + koff); \
        *(uint4*)((char*)s + c * (K2_) + (koff ^ ((c & 7) << 4))) = v;          \
    }

#define MM_LOOP(A_, Kc_, K2_, acc0_, acc1_)                                     \
    {                                                                           \
        const char* a0p = (const char*)((A_) + (size_t)r0 * (Kc_)) + lq * 16;   \
        const char* a1p = a0p + 16 * (Kc_) * 2;                                 \
        for (int k0 = 0; k0 < (Kc_); k0 += 32) {                                \
            bf16x8 a0 = *(const bf16x8*)(a0p + k0 * 2);                         \
            bf16x8 a1 = *(const bf16x8*)(a1p + k0 * 2);                         \
            int kb = (k0 + lq * 8) * 2;                                         \
            _Pragma("unroll")                                                   \
            for (int nt = 0; nt < 8; ++nt) {                                    \
                int c = nt * 16 + l15;                                          \
                bf16x8 b = *(const bf16x8*)((const char*)s + c * (K2_) + (kb ^ ((c & 7) << 4))); \
                acc0_[nt] = __builtin_amdgcn_mfma_f32_16x16x32_bf16(a0, b, acc0_[nt], 0, 0, 0); \
                acc1_[nt] = __builtin_amdgcn_mfma_f32_16x16x32_bf16(a1, b, acc1_[nt], 0, 0, 0); \
            }                                                                   \
        }                                                                       \
    }

#define BNT 128

// GEMM1: h1 = relu(bn1(h @ W1 + b1))   [NPAD,128]x[128,256] -> bf16 [NPAD,256]
__global__ __launch_bounds__(256) void k_mm1(
    const ushort* __restrict__ A, const ushort* __restrict__ Wt,
    const float* __restrict__ bb, const float* __restrict__ g,
    const float* __restrict__ bt, const float* __restrict__ m,
    const float* __restrict__ vv, ushort* __restrict__ C) {
    __shared__ ushort s[BNT * 128];                  // 32 KB
    int tid = threadIdx.x;
    int bm = blockIdx.x >> 1, bn = blockIdx.x & 1;
    int ncol0 = bn * BNT;
    STAGE_WT(Wt, 128, 256);
    __syncthreads();
    int wid = tid >> 6, lane = tid & 63;
    int l15 = lane & 15, lq = lane >> 4;
    int r0 = bm * 128 + wid * 32 + l15;
    f32x4 acc0[8] = {}, acc1[8] = {};
    MM_LOOP(A, 128, 256, acc0, acc1);
#pragma unroll
    for (int nt = 0; nt < 8; ++nt) {
        int col = ncol0 + nt * 16 + l15;
        float sc = g[col] * rsqrtf(vv[col] + 1e-5f);
        float bo = (bb[col] - m[col]) * sc + bt[col];
        int rb = bm * 128 + wid * 32 + lq * 4;
#pragma unroll
        for (int r = 0; r < 4; ++r) {
            C[(size_t)(rb + r) * KDOUT + col] = f2bf(fmaxf(acc0[nt][r] * sc + bo, 0.f));
            C[(size_t)(rb + 16 + r) * KDOUT + col] = f2bf(fmaxf(acc1[nt][r] * sc + bo, 0.f));
        }
    }
}

// GEMM2 fused: out = relu( relu(bn2(h1 @ W2 + b2)) + x @ Wres )
__global__ __launch_bounds__(256) void k_mm2(
    const ushort* __restrict__ H1, const ushort* __restrict__ W2t,
    const ushort* __restrict__ X, const ushort* __restrict__ Wrt,
    const float* __restrict__ bb, const float* __restrict__ g,
    const float* __restrict__ bt, const float* __restrict__ m,
    const float* __restrict__ vv, float* __restrict__ OUT) {
    __shared__ ushort s[BNT * 256];                  // 64 KB
    int tid = threadIdx.x;
    int bm = blockIdx.x >> 1, bn = blockIdx.x & 1;
    int ncol0 = bn * BNT;
    int wid = tid >> 6, lane = tid & 63;
    int l15 = lane & 15, lq = lane >> 4;
    int r0 = bm * 128 + wid * 32 + l15;

    STAGE_WT(W2t, 256, 512);                         // phase 1: h1 @ W2
    __syncthreads();
    f32x4 acc0[8] = {}, acc1[8] = {};
    MM_LOOP(H1, 256, 512, acc0, acc1);

    __syncthreads();                                 // re-stage: Wres^T
    STAGE_WT(Wrt, 128, 256);
    __syncthreads();
    f32x4 acd0[8] = {}, acd1[8] = {};
    MM_LOOP(X, 128, 256, acd0, acd1);

#pragma unroll
    for (int nt = 0; nt < 8; ++nt) {
        int col = ncol0 + nt * 16 + l15;
        float sc = g[col] * rsqrtf(vv[col] + 1e-5f);
        float bo = (bb[col] - m[col]) * sc + bt[col];
        int rb = bm * 128 + wid * 32 + lq * 4;
#pragma unroll
        for (int r = 0; r < 4; ++r) {
            int row0 = rb + r, row1 = rb + 16 + r;
            float t0 = fmaxf(acc0[nt][r] * sc + bo, 0.f);
            float t1 = fmaxf(acc1[nt][r] * sc + bo, 0.f);
            if (row0 < NN) OUT[(size_t)row0 * KDOUT + col] = fmaxf(t0 + acd0[nt][r], 0.f);
            if (row1 < NN) OUT[(size_t)row1 * KDOUT + col] = fmaxf(t1 + acd1[nt][r], 0.f);
        }
    }
}

// ------------------------------------------------------------------- launch
extern "C" void kernel_launch(void* const* d_in, const int* in_sizes, int n_in,
                              void* d_out, int out_size, void* d_ws, size_t ws_size,
                              hipStream_t stream) {
    const float* x    = (const float*)d_in[0];
    const int*   ei   = (const int*)d_in[1];
    const float* eps  = (const float*)d_in[2];
    const float* W1   = (const float*)d_in[3];
    const float* b1   = (const float*)d_in[4];
    const float* g1   = (const float*)d_in[5];
    const float* bt1  = (const float*)d_in[6];
    const float* m1   = (const float*)d_in[7];
    const float* v1   = (const float*)d_in[8];
    const float* W2   = (const float*)d_in[9];
    const float* b2   = (const float*)d_in[10];
    const float* g2   = (const float*)d_in[11];
    const float* bt2  = (const float*)d_in[12];
    const float* m2   = (const float*)d_in[13];
    const float* v2   = (const float*)d_in[14];
    const float* Wres = (const float*)d_in[15];
    float* out = (float*)d_out;

    char* w = (char*)d_ws;
    ushort* xb  = (ushort*)w;                 w += (size_t)NPAD * KDIN * 2;   // 10.3 MB
    ushort* hb  = (ushort*)w;                 w += (size_t)NPAD * KDIN * 2;   // 10.3 MB
    ushort* h1b = (ushort*)w;                 w += (size_t)NPAD * KDOUT * 2;  // 20.5 MB
    ushort* w1t = (ushort*)w;                 w += 256 * 128 * 2;
    ushort* w2t = (ushort*)w;                 w += 256 * 256 * 2;
    ushort* wrt = (ushort*)w;                 w += 256 * 128 * 2;
    int* deg    = (int*)w;                    w += NN * 4;
    int* starts = (int*)w;                    w += NN * 4;
    int* csr    = (int*)w;                    w += (size_t)EE * 4;

    // zero pads (rows NN..NPAD) so padded GEMM rows can't produce NaN
    hipMemsetAsync(xb + (size_t)NN * KDIN, 0, (NPAD - NN) * KDIN * 2, stream);
    hipMemsetAsync(hb + (size_t)NN * KDIN, 0, (NPAD - NN) * KDIN * 2, stream);
    hipMemsetAsync(deg, 0, NN * sizeof(int), stream);

    k_cvt<<<(NN * KDIN / 8 + 255) / 256, 256, 0, stream>>>((const float4*)x, xb);
    k_wt<<<(KDIN * KDOUT + 255) / 256, 256, 0, stream>>>(W1, w1t, KDIN, KDOUT);
    k_wt<<<(KDOUT * KDOUT + 255) / 256, 256, 0, stream>>>(W2, w2t, KDOUT, KDOUT);
    k_wt<<<(KDIN * KDOUT + 255) / 256, 256, 0, stream>>>(Wres, wrt, KDIN, KDOUT);

    k_hist<<<(EE + 255) / 256, 256, 0, stream>>>(ei, deg);
    k_scan<<<1, 1024, 0, stream>>>(deg, starts);
    k_fill<<<(EE + 255) / 256, 256, 0, stream>>>(ei, starts, csr);
    k_gather<<<(NN * 16 + 255) / 256, 256, 0, stream>>>(xb, starts, csr, eps, hb);

    const int grid = (NPAD / 128) * 2;        // 313 m-tiles x 2 n-tiles
    k_mm1<<<grid, 256, 0, stream>>>(hb, w1t, b1, g1, bt1, m1, v1, h1b);
    k_mm2<<<grid, 256, 0, stream>>>(h1b, w2t, xb, wrt, b2, g2, bt2, m2, v2, out);
}

// Round 4
// 187.536 us; speedup vs baseline: 6.8116x; 1.0728x over previous
//
#include <hip/hip_runtime.h>

#define NN 40000
#define NPAD 40064          // 313 * 128
#define EE 640000
#define KDIN 128
#define KDOUT 256

typedef __attribute__((ext_vector_type(8))) short bf16x8;   // 8 bf16 = 4 VGPR
typedef __attribute__((ext_vector_type(4))) float f32x4;    // MFMA acc

static __device__ __forceinline__ unsigned short f2bf(float f) {
    union { float f; unsigned int u; } v; v.f = f;
    unsigned int r = (v.u + 0x7FFFu + ((v.u >> 16) & 1u)) >> 16;  // RNE
    return (unsigned short)r;
}
static __device__ __forceinline__ float bf2f(unsigned short h) {
    union { unsigned int u; float f; } v; v.u = ((unsigned int)h) << 16;
    return v.f;
}

// ------------------------------------------------------------------- prep
// One fused kernel, blockIdx-partitioned:
//   [0, 2504)      : x -> bf16 (NPAD rows; pad rows = 0)
//   [2504, 3016)   : W1/W2/Wres transpose+convert -> w1t|w2t|wrt (concat)
//   [3016, 3056)   : deg = 0
//   [3056, 3060)   : hb pad rows = 0
#define PREP_GRID 3060
__global__ __launch_bounds__(256) void k_prep(
    const float* __restrict__ x,
    const float* __restrict__ W1, const float* __restrict__ W2,
    const float* __restrict__ Wres,
    ushort* __restrict__ xb, ushort* __restrict__ wt_all,
    int* __restrict__ deg, ushort* __restrict__ hb) {
    int b = blockIdx.x, tid = threadIdx.x;
    if (b < 2504) {                                  // x convert, 8 elems/thread
        int i = b * 256 + tid;                       // elem8 index
        int row = i >> 4;
        uint4 o = {0, 0, 0, 0};
        if (row < NN) {
            const float4* xp = (const float4*)x + (size_t)i * 2;
            float4 a = xp[0], c = xp[1];
            o.x = (unsigned)f2bf(a.x) | ((unsigned)f2bf(a.y) << 16);
            o.y = (unsigned)f2bf(a.z) | ((unsigned)f2bf(a.w) << 16);
            o.z = (unsigned)f2bf(c.x) | ((unsigned)f2bf(c.y) << 16);
            o.w = (unsigned)f2bf(c.z) | ((unsigned)f2bf(c.w) << 16);
        }
        if (row < NPAD) *(uint4*)(xb + (size_t)i * 8) = o;
    } else if (b < 3016) {                           // weight transposes
        int j = (b - 2504) * 256 + tid;              // concat index
        if (j < 32768) {                             // w1t [256][128]
            int c = j >> 7, r = j & 127;
            wt_all[j] = f2bf(W1[r * KDOUT + c]);
        } else if (j < 98304) {                      // w2t [256][256]
            int j2 = j - 32768;
            int c = j2 >> 8, r = j2 & 255;
            wt_all[j] = f2bf(W2[r * KDOUT + c]);
        } else {                                     // wrt [256][128]
            int j3 = j - 98304;
            int c = j3 >> 7, r = j3 & 127;
            wt_all[j] = f2bf(Wres[r * KDOUT + c]);
        }
    } else if (b < 3056) {                           // deg = 0
        int idx = (b - 3016) * 256 + tid;
        if (idx < NN / 4) ((uint4*)deg)[idx] = (uint4){0, 0, 0, 0};
    } else {                                         // hb pad rows = 0
        int idx = (b - 3056) * 256 + tid;            // 1024 uint4 = 16 KB
        ((uint4*)(hb + (size_t)NN * KDIN))[idx] = (uint4){0, 0, 0, 0};
    }
}

// ------------------------------------------------------------- CSR build
__global__ __launch_bounds__(256) void k_hist(const int* __restrict__ ei,
                                              int* __restrict__ deg) {
    int e = blockIdx.x * 256 + threadIdx.x;
    if (e < EE) atomicAdd(&deg[ei[EE + e]], 1);
}

__global__ __launch_bounds__(1024) void k_scan(const int* __restrict__ deg,
                                               int* __restrict__ starts) {
    __shared__ int wsum[16];
    __shared__ int carry;
    int t = threadIdx.x, lane = t & 63, wid = t >> 6;
    if (t == 0) carry = 0;
    __syncthreads();
    for (int base = 0; base < NN; base += 1024) {
        int i = base + t;
        int v = (i < NN) ? deg[i] : 0;
        int incl = v;
#pragma unroll
        for (int off = 1; off < 64; off <<= 1) {
            int u = __shfl_up(incl, off, 64);
            if (lane >= off) incl += u;
        }
        if (lane == 63) wsum[wid] = incl;
        __syncthreads();
        if (wid == 0 && lane < 16) {
            int s = wsum[lane];
            int si = s;
#pragma unroll
            for (int off = 1; off < 16; off <<= 1) {
                int u = __shfl_up(si, off, 64);
                if (lane >= off) si += u;
            }
            wsum[lane] = si - s;                     // exclusive wave offset
        }
        __syncthreads();
        if (i < NN) starts[i] = carry + wsum[wid] + incl - v;
        __syncthreads();                             // all carry reads done
        if (t == 1023) carry += wsum[15] + incl;     // chunk total
    }
}

// fill csr_src; afterwards starts[i] == end_i
__global__ __launch_bounds__(256) void k_fill(const int* __restrict__ ei,
                                              int* __restrict__ starts,
                                              int* __restrict__ csr_src) {
    int e = blockIdx.x * 256 + threadIdx.x;
    if (e >= EE) return;
    int src = ei[e];
    int dst = ei[EE + e];
    int pos = atomicAdd(&starts[dst], 1);
    csr_src[pos] = src;
}

// ---------------------------------------------------------------- gather
// 16 lanes per node, 8 bf16 per lane. h = (1+eps)*x + sum_{src} x[src]
__global__ __launch_bounds__(256) void k_gather(const ushort* __restrict__ xb,
                                                const int* __restrict__ ends,
                                                const int* __restrict__ csr_src,
                                                const float* __restrict__ eps,
                                                ushort* __restrict__ hb) {
    int gid = blockIdx.x * 256 + threadIdx.x;
    int node = gid >> 4, lane = gid & 15;
    if (node >= NN) return;
    int start = node ? ends[node - 1] : 0;
    int end = ends[node];
    float s = 1.0f + eps[0];
    float acc[8];
    {
        uint4 me = *(const uint4*)(xb + (size_t)node * KDIN + lane * 8);
        acc[0] = bf2f((unsigned short)(me.x & 0xffff)) * s;
        acc[1] = bf2f((unsigned short)(me.x >> 16)) * s;
        acc[2] = bf2f((unsigned short)(me.y & 0xffff)) * s;
        acc[3] = bf2f((unsigned short)(me.y >> 16)) * s;
        acc[4] = bf2f((unsigned short)(me.z & 0xffff)) * s;
        acc[5] = bf2f((unsigned short)(me.z >> 16)) * s;
        acc[6] = bf2f((unsigned short)(me.w & 0xffff)) * s;
        acc[7] = bf2f((unsigned short)(me.w >> 16)) * s;
    }
    for (int e = start; e < end; ++e) {
        int src = csr_src[e];
        uint4 v = *(const uint4*)(xb + (size_t)src * KDIN + lane * 8);
        acc[0] += bf2f((unsigned short)(v.x & 0xffff));
        acc[1] += bf2f((unsigned short)(v.x >> 16));
        acc[2] += bf2f((unsigned short)(v.y & 0xffff));
        acc[3] += bf2f((unsigned short)(v.y >> 16));
        acc[4] += bf2f((unsigned short)(v.z & 0xffff));
        acc[5] += bf2f((unsigned short)(v.z >> 16));
        acc[6] += bf2f((unsigned short)(v.w & 0xffff));
        acc[7] += bf2f((unsigned short)(v.w >> 16));
    }
    uint4 o;
    o.x = (unsigned)f2bf(acc[0]) | ((unsigned)f2bf(acc[1]) << 16);
    o.y = (unsigned)f2bf(acc[2]) | ((unsigned)f2bf(acc[3]) << 16);
    o.z = (unsigned)f2bf(acc[4]) | ((unsigned)f2bf(acc[5]) << 16);
    o.w = (unsigned)f2bf(acc[6]) | ((unsigned)f2bf(acc[7]) << 16);
    *(uint4*)(hb + (size_t)node * KDIN + lane * 8) = o;
}

// ------------------------------------------------------------ MFMA GEMMs
// Block: 256 threads = 4 waves. Tile BM=128 x BN=128. Wave w: rows w*32..+31.
// W^T column slice staged in LDS, XOR-swizzled: byte ^= (col&7)<<4.
// A-fragments loaded directly from global (L3-resident, read once per block).

#define STAGE_WT(Wt_, Kc_, K2_)                                                 \
    for (int id = tid; id < BNT * (K2_) / 16; id += 256) {                      \
        int c = id / ((K2_) / 16);                                              \
        int koff = (id % ((K2_) / 16)) * 16;                                    \
        uint4 v = *(const uint4*)((const char*)((Wt_) + (size_t)(ncol0 + c) * (Kc_)) + koff); \
        *(uint4*)((char*)s + c * (K2_) + (koff ^ ((c & 7) << 4))) = v;          \
    }

#define MM_LOOP(A_, Kc_, K2_, acc0_, acc1_)                                     \
    {                                                                           \
        const char* a0p = (const char*)((A_) + (size_t)r0 * (Kc_)) + lq * 16;   \
        const char* a1p = a0p + 16 * (Kc_) * 2;                                 \
        for (int k0 = 0; k0 < (Kc_); k0 += 32) {                                \
            bf16x8 a0 = *(const bf16x8*)(a0p + k0 * 2);                         \
            bf16x8 a1 = *(const bf16x8*)(a1p + k0 * 2);                         \
            int kb = (k0 + lq * 8) * 2;                                         \
            _Pragma("unroll")                                                   \
            for (int nt = 0; nt < 8; ++nt) {                                    \
                int c = nt * 16 + l15;                                          \
                bf16x8 b = *(const bf16x8*)((const char*)s + c * (K2_) + (kb ^ ((c & 7) << 4))); \
                acc0_[nt] = __builtin_amdgcn_mfma_f32_16x16x32_bf16(a0, b, acc0_[nt], 0, 0, 0); \
                acc1_[nt] = __builtin_amdgcn_mfma_f32_16x16x32_bf16(a1, b, acc1_[nt], 0, 0, 0); \
            }                                                                   \
        }                                                                       \
    }

#define BNT 128

// GEMM1: h1 = relu(bn1(h @ W1 + b1))   [NPAD,128]x[128,256] -> bf16 [NPAD,256]
__global__ __launch_bounds__(256) void k_mm1(
    const ushort* __restrict__ A, const ushort* __restrict__ Wt,
    const float* __restrict__ bb, const float* __restrict__ g,
    const float* __restrict__ bt, const float* __restrict__ m,
    const float* __restrict__ vv, ushort* __restrict__ C) {
    __shared__ ushort s[BNT * 128];                  // 32 KB
    int tid = threadIdx.x;
    int bm = blockIdx.x >> 1, bn = blockIdx.x & 1;
    int ncol0 = bn * BNT;
    STAGE_WT(Wt, 128, 256);
    __syncthreads();
    int wid = tid >> 6, lane = tid & 63;
    int l15 = lane & 15, lq = lane >> 4;
    int r0 = bm * 128 + wid * 32 + l15;
    f32x4 acc0[8] = {}, acc1[8] = {};
    MM_LOOP(A, 128, 256, acc0, acc1);
#pragma unroll
    for (int nt = 0; nt < 8; ++nt) {
        int col = ncol0 + nt * 16 + l15;
        float sc = g[col] * rsqrtf(vv[col] + 1e-5f);
        float bo = (bb[col] - m[col]) * sc + bt[col];
        int rb = bm * 128 + wid * 32 + lq * 4;
#pragma unroll
        for (int r = 0; r < 4; ++r) {
            C[(size_t)(rb + r) * KDOUT + col] = f2bf(fmaxf(acc0[nt][r] * sc + bo, 0.f));
            C[(size_t)(rb + 16 + r) * KDOUT + col] = f2bf(fmaxf(acc1[nt][r] * sc + bo, 0.f));
        }
    }
}

// GEMM2 fused: out = relu( relu(bn2(h1 @ W2 + b2)) + x @ Wres )
__global__ __launch_bounds__(256) void k_mm2(
    const ushort* __restrict__ H1, const ushort* __restrict__ W2t,
    const ushort* __restrict__ X, const ushort* __restrict__ Wrt,
    const float* __restrict__ bb, const float* __restrict__ g,
    const float* __restrict__ bt, const float* __restrict__ m,
    const float* __restrict__ vv, float* __restrict__ OUT) {
    __shared__ ushort s[BNT * 256];                  // 64 KB
    int tid = threadIdx.x;
    int bm = blockIdx.x >> 1, bn = blockIdx.x & 1;
    int ncol0 = bn * BNT;
    int wid = tid >> 6, lane = tid & 63;
    int l15 = lane & 15, lq = lane >> 4;
    int r0 = bm * 128 + wid * 32 + l15;

    STAGE_WT(W2t, 256, 512);                         // phase 1: h1 @ W2
    __syncthreads();
    f32x4 acc0[8] = {}, acc1[8] = {};
    MM_LOOP(H1, 256, 512, acc0, acc1);

    __syncthreads();                                 // re-stage: Wres^T
    STAGE_WT(Wrt, 128, 256);
    __syncthreads();
    f32x4 acd0[8] = {}, acd1[8] = {};
    MM_LOOP(X, 128, 256, acd0, acd1);

#pragma unroll
    for (int nt = 0; nt < 8; ++nt) {
        int col = ncol0 + nt * 16 + l15;
        float sc = g[col] * rsqrtf(vv[col] + 1e-5f);
        float bo = (bb[col] - m[col]) * sc + bt[col];
        int rb = bm * 128 + wid * 32 + lq * 4;
#pragma unroll
        for (int r = 0; r < 4; ++r) {
            int row0 = rb + r, row1 = rb + 16 + r;
            float t0 = fmaxf(acc0[nt][r] * sc + bo, 0.f);
            float t1 = fmaxf(acc1[nt][r] * sc + bo, 0.f);
            if (row0 < NN) OUT[(size_t)row0 * KDOUT + col] = fmaxf(t0 + acd0[nt][r], 0.f);
            if (row1 < NN) OUT[(size_t)row1 * KDOUT + col] = fmaxf(t1 + acd1[nt][r], 0.f);
        }
    }
}

// ------------------------------------------------------------------- launch
extern "C" void kernel_launch(void* const* d_in, const int* in_sizes, int n_in,
                              void* d_out, int out_size, void* d_ws, size_t ws_size,
                              hipStream_t stream) {
    const float* x    = (const float*)d_in[0];
    const int*   ei   = (const int*)d_in[1];
    const float* eps  = (const float*)d_in[2];
    const float* W1   = (const float*)d_in[3];
    const float* b1   = (const float*)d_in[4];
    const float* g1   = (const float*)d_in[5];
    const float* bt1  = (const float*)d_in[6];
    const float* m1   = (const float*)d_in[7];
    const float* v1   = (const float*)d_in[8];
    const float* W2   = (const float*)d_in[9];
    const float* b2   = (const float*)d_in[10];
    const float* g2   = (const float*)d_in[11];
    const float* bt2  = (const float*)d_in[12];
    const float* m2   = (const float*)d_in[13];
    const float* v2   = (const float*)d_in[14];
    const float* Wres = (const float*)d_in[15];
    float* out = (float*)d_out;

    char* w = (char*)d_ws;
    ushort* xb  = (ushort*)w;                 w += (size_t)NPAD * KDIN * 2;   // 10.3 MB
    ushort* hb  = (ushort*)w;                 w += (size_t)NPAD * KDIN * 2;   // 10.3 MB
    ushort* h1b = (ushort*)w;                 w += (size_t)NPAD * KDOUT * 2;  // 20.5 MB
    ushort* w1t = (ushort*)w;                 w += 256 * 128 * 2;
    ushort* w2t = (ushort*)w;                 w += 256 * 256 * 2;
    ushort* wrt = (ushort*)w;                 w += 256 * 128 * 2;
    int* deg    = (int*)w;                    w += NN * 4;
    int* starts = (int*)w;                    w += NN * 4;
    int* csr    = (int*)w;                    w += (size_t)EE * 4;

    // fused prep: x->bf16 (incl. zero pads), weight transposes, deg=0, hb pads=0
    k_prep<<<PREP_GRID, 256, 0, stream>>>(x, W1, W2, Wres, xb, w1t, deg, hb);

    k_hist<<<(EE + 255) / 256, 256, 0, stream>>>(ei, deg);
    k_scan<<<1, 1024, 0, stream>>>(deg, starts);
    k_fill<<<(EE + 255) / 256, 256, 0, stream>>>(ei, starts, csr);
    k_gather<<<(NN * 16 + 255) / 256, 256, 0, stream>>>(xb, starts, csr, eps, hb);

    const int grid = (NPAD / 128) * 2;        // 313 m-tiles x 2 n-tiles
    k_mm1<<<grid, 256, 0, stream>>>(hb, w1t, b1, g1, bt1, m1, v1, h1b);
    k_mm2<<<grid, 256, 0, stream>>>(h1b, w2t, xb, wrt, b2, g2, bt2, m2, v2, out);
}

// Round 5
// 124.387 us; speedup vs baseline: 10.2697x; 1.5077x over previous
//
#include <hip/hip_runtime.h>

#define NN 40000
#define NPAD 40064          // 313 * 128
#define EE 640000
#define KDIN 128
#define KDOUT 256

#define NB 157              // coarse buckets: dst >> 8
#define CAP 6144            // per-bucket record capacity (mean 4076, +32 sigma)

typedef __attribute__((ext_vector_type(8))) short bf16x8;   // 8 bf16 = 4 VGPR
typedef __attribute__((ext_vector_type(4))) float f32x4;    // MFMA acc

static __device__ __forceinline__ unsigned short f2bf(float f) {
    union { float f; unsigned int u; } v; v.f = f;
    unsigned int r = (v.u + 0x7FFFu + ((v.u >> 16) & 1u)) >> 16;  // RNE
    return (unsigned short)r;
}
static __device__ __forceinline__ float bf2f(unsigned short h) {
    union { unsigned int u; float f; } v; v.u = ((unsigned int)h) << 16;
    return v.f;
}

// ------------------------------------------------------------------- prep
//   [0, 2504)      : x -> bf16 (NPAD rows; pad rows = 0)
//   [2504, 3016)   : W1/W2/Wres transpose+convert -> w1t|w2t|wrt (concat)
//   [3016, 3020)   : hb pad rows = 0
//   [3020, 3021)   : bucket cursors = 0
#define PREP_GRID 3021
__global__ __launch_bounds__(256) void k_prep(
    const float* __restrict__ x,
    const float* __restrict__ W1, const float* __restrict__ W2,
    const float* __restrict__ Wres,
    ushort* __restrict__ xb, ushort* __restrict__ wt_all,
    int* __restrict__ cur, ushort* __restrict__ hb) {
    int b = blockIdx.x, tid = threadIdx.x;
    if (b < 2504) {                                  // x convert, 8 elems/thread
        int i = b * 256 + tid;                       // elem8 index
        int row = i >> 4;
        uint4 o = {0, 0, 0, 0};
        if (row < NN) {
            const float4* xp = (const float4*)x + (size_t)i * 2;
            float4 a = xp[0], c = xp[1];
            o.x = (unsigned)f2bf(a.x) | ((unsigned)f2bf(a.y) << 16);
            o.y = (unsigned)f2bf(a.z) | ((unsigned)f2bf(a.w) << 16);
            o.z = (unsigned)f2bf(c.x) | ((unsigned)f2bf(c.y) << 16);
            o.w = (unsigned)f2bf(c.z) | ((unsigned)f2bf(c.w) << 16);
        }
        if (row < NPAD) *(uint4*)(xb + (size_t)i * 8) = o;
    } else if (b < 3016) {                           // weight transposes
        int j = (b - 2504) * 256 + tid;              // concat index
        if (j < 32768) {                             // w1t [256][128]
            int c = j >> 7, r = j & 127;
            wt_all[j] = f2bf(W1[r * KDOUT + c]);
        } else if (j < 98304) {                      // w2t [256][256]
            int j2 = j - 32768;
            int c = j2 >> 8, r = j2 & 255;
            wt_all[j] = f2bf(W2[r * KDOUT + c]);
        } else {                                     // wrt [256][128]
            int j3 = j - 98304;
            int c = j3 >> 7, r = j3 & 127;
            wt_all[j] = f2bf(Wres[r * KDOUT + c]);
        }
    } else if (b < 3020) {                           // hb pad rows = 0
        int idx = (b - 3016) * 256 + tid;            // 1024 uint4 = 16 KB
        ((uint4*)(hb + (size_t)NN * KDIN))[idx] = (uint4){0, 0, 0, 0};
    } else {                                         // bucket cursors = 0
        if (tid < NB) cur[tid] = 0;
    }
}

// ----------------------------------------------------- phase A: edge binning
// Each block: 4096 edges -> LDS bucket-sort by dst>>8 -> coalesced run writes.
// Record: (dst & 255) << 16 | src   (src < 65536)
__global__ __launch_bounds__(256) void k_binA(const int* __restrict__ ei,
                                              int* __restrict__ cur,
                                              unsigned int* __restrict__ recs) {
    __shared__ int cnt[160], lstart[160], lcur[160], gbase[160];
    __shared__ int sw[256];
    __shared__ unsigned int lrec[4096];
    __shared__ int laddr[4096];
    int tid = threadIdx.x;
    int e0 = blockIdx.x * 4096;
    int e1 = min(e0 + 4096, EE);
    int ns = e1 - e0;

    if (tid < NB) cnt[tid] = 0;
    __syncthreads();
    for (int s = tid; s < ns; s += 256)
        atomicAdd(&cnt[ei[EE + e0 + s] >> 8], 1);
    __syncthreads();
    // inclusive scan over 256 slots (cnt beyond NB treated as 0)
    sw[tid] = (tid < NB) ? cnt[tid] : 0;
    __syncthreads();
    for (int off = 1; off < 256; off <<= 1) {
        int add = (tid >= off) ? sw[tid - off] : 0;
        __syncthreads();
        sw[tid] += add;
        __syncthreads();
    }
    if (tid < NB) {
        int st = sw[tid] - cnt[tid];                 // block-local exclusive
        lstart[tid] = st;
        lcur[tid] = st;
        gbase[tid] = atomicAdd(&cur[tid], cnt[tid]); // reserve global run
    }
    __syncthreads();
    for (int s = tid; s < ns; s += 256) {
        int e = e0 + s;
        int src = ei[e];
        int dst = ei[EE + e];
        int b = dst >> 8;
        int p = atomicAdd(&lcur[b], 1);
        lrec[p] = ((unsigned int)(dst & 255) << 16) | (unsigned int)src;
        laddr[p] = b * CAP + gbase[b] + (p - lstart[b]);
    }
    __syncthreads();
    for (int s = tid; s < ns; s += 256)              // piecewise-contiguous
        recs[laddr[s]] = lrec[s];
}

// -------------------------------------------- phase B: aggregate per bucket
// Block (b, half): bucket b (256 dst nodes), dims [half*64, half*64+64).
// LDS counting-sort records by dst-low, then register-accumulated gather.
__global__ __launch_bounds__(256) void k_aggB(const unsigned int* __restrict__ recs,
                                              const int* __restrict__ cur,
                                              const ushort* __restrict__ xb,
                                              const float* __restrict__ eps,
                                              ushort* __restrict__ hb) {
    __shared__ ushort lsrc[CAP];
    __shared__ int lcnt[256], lst[256], lcur[256];
    __shared__ int sw[256];
    int tid = threadIdx.x;
    int b = blockIdx.x >> 1, half = blockIdx.x & 1;
    int cnt = cur[b];
    const unsigned int* rb = recs + (size_t)b * CAP;

    lcnt[tid] = 0;
    __syncthreads();
    for (int s = tid; s < cnt; s += 256)
        atomicAdd(&lcnt[rb[s] >> 16], 1);
    __syncthreads();
    sw[tid] = lcnt[tid];
    __syncthreads();
    for (int off = 1; off < 256; off <<= 1) {
        int add = (tid >= off) ? sw[tid - off] : 0;
        __syncthreads();
        sw[tid] += add;
        __syncthreads();
    }
    int excl = sw[tid] - lcnt[tid];
    lst[tid] = excl;
    lcur[tid] = excl;
    __syncthreads();
    for (int s = tid; s < cnt; s += 256) {
        unsigned int r = rb[s];
        int p = atomicAdd(&lcur[r >> 16], 1);
        lsrc[p] = (ushort)(r & 0xffff);
    }
    __syncthreads();

    int g = tid >> 3, lane = tid & 7;                // 32 groups x 8 lanes
    float s1 = 1.0f + eps[0];
    for (int d = g; d < 256; d += 32) {
        int node = b * 256 + d;
        if (node >= NN) continue;
        int st = lst[d], en = st + lcnt[d];
        const uint4* xrow = (const uint4*)(xb + (size_t)node * KDIN) + half * 8;
        uint4 me = xrow[lane];
        float a[8], a2[8];
        a[0] = bf2f((ushort)(me.x & 0xffff)) * s1; a[1] = bf2f((ushort)(me.x >> 16)) * s1;
        a[2] = bf2f((ushort)(me.y & 0xffff)) * s1; a[3] = bf2f((ushort)(me.y >> 16)) * s1;
        a[4] = bf2f((ushort)(me.z & 0xffff)) * s1; a[5] = bf2f((ushort)(me.z >> 16)) * s1;
        a[6] = bf2f((ushort)(me.w & 0xffff)) * s1; a[7] = bf2f((ushort)(me.w >> 16)) * s1;
#pragma unroll
        for (int i = 0; i < 8; ++i) a2[i] = 0.f;
        int e = st;
        for (; e + 1 < en; e += 2) {                 // 2 loads in flight
            int s0 = lsrc[e], sB = lsrc[e + 1];
            uint4 v0 = *((const uint4*)(xb + (size_t)s0 * KDIN) + half * 8 + lane);
            uint4 v1 = *((const uint4*)(xb + (size_t)sB * KDIN) + half * 8 + lane);
            a[0] += bf2f((ushort)(v0.x & 0xffff)); a[1] += bf2f((ushort)(v0.x >> 16));
            a[2] += bf2f((ushort)(v0.y & 0xffff)); a[3] += bf2f((ushort)(v0.y >> 16));
            a[4] += bf2f((ushort)(v0.z & 0xffff)); a[5] += bf2f((ushort)(v0.z >> 16));
            a[6] += bf2f((ushort)(v0.w & 0xffff)); a[7] += bf2f((ushort)(v0.w >> 16));
            a2[0] += bf2f((ushort)(v1.x & 0xffff)); a2[1] += bf2f((ushort)(v1.x >> 16));
            a2[2] += bf2f((ushort)(v1.y & 0xffff)); a2[3] += bf2f((ushort)(v1.y >> 16));
            a2[4] += bf2f((ushort)(v1.z & 0xffff)); a2[5] += bf2f((ushort)(v1.z >> 16));
            a2[6] += bf2f((ushort)(v1.w & 0xffff)); a2[7] += bf2f((ushort)(v1.w >> 16));
        }
        if (e < en) {
            int s0 = lsrc[e];
            uint4 v0 = *((const uint4*)(xb + (size_t)s0 * KDIN) + half * 8 + lane);
            a[0] += bf2f((ushort)(v0.x & 0xffff)); a[1] += bf2f((ushort)(v0.x >> 16));
            a[2] += bf2f((ushort)(v0.y & 0xffff)); a[3] += bf2f((ushort)(v0.y >> 16));
            a[4] += bf2f((ushort)(v0.z & 0xffff)); a[5] += bf2f((ushort)(v0.z >> 16));
            a[6] += bf2f((ushort)(v0.w & 0xffff)); a[7] += bf2f((ushort)(v0.w >> 16));
        }
#pragma unroll
        for (int i = 0; i < 8; ++i) a[i] += a2[i];
        uint4 o;
        o.x = (unsigned)f2bf(a[0]) | ((unsigned)f2bf(a[1]) << 16);
        o.y = (unsigned)f2bf(a[2]) | ((unsigned)f2bf(a[3]) << 16);
        o.z = (unsigned)f2bf(a[4]) | ((unsigned)f2bf(a[5]) << 16);
        o.w = (unsigned)f2bf(a[6]) | ((unsigned)f2bf(a[7]) << 16);
        *((uint4*)(hb + (size_t)node * KDIN) + half * 8 + lane) = o;
    }
}

// ------------------------------------------------------------ MFMA GEMMs
// Block: 256 threads = 4 waves. Tile BM=128 x BN=128. Wave w: rows w*32..+31.
// W^T column slice staged in LDS, XOR-swizzled: byte ^= (col&7)<<4.
// A-fragments loaded directly from global (L3-resident, read once per block).

#define STAGE_WT(Wt_, Kc_, K2_)                                                 \
    for (int id = tid; id < BNT * (K2_) / 16; id += 256) {                      \
        int c = id / ((K2_) / 16);                                              \
        int koff = (id % ((K2_) / 16)) * 16;                                    \
        uint4 v = *(const uint4*)((const char*)((Wt_) + (size_t)(ncol0 + c) * (Kc_)) + koff); \
        *(uint4*)((char*)s + c * (K2_) + (koff ^ ((c & 7) << 4))) = v;          \
    }

#define MM_LOOP(A_, Kc_, K2_, acc0_, acc1_)                                     \
    {                                                                           \
        const char* a0p = (const char*)((A_) + (size_t)r0 * (Kc_)) + lq * 16;   \
        const char* a1p = a0p + 16 * (Kc_) * 2;                                 \
        for (int k0 = 0; k0 < (Kc_); k0 += 32) {                                \
            bf16x8 a0 = *(const bf16x8*)(a0p + k0 * 2);                         \
            bf16x8 a1 = *(const bf16x8*)(a1p + k0 * 2);                         \
            int kb = (k0 + lq * 8) * 2;                                         \
            _Pragma("unroll")                                                   \
            for (int nt = 0; nt < 8; ++nt) {                                    \
                int c = nt * 16 + l15;                                          \
                bf16x8 b = *(const bf16x8*)((const char*)s + c * (K2_) + (kb ^ ((c & 7) << 4))); \
                acc0_[nt] = __builtin_amdgcn_mfma_f32_16x16x32_bf16(a0, b, acc0_[nt], 0, 0, 0); \
                acc1_[nt] = __builtin_amdgcn_mfma_f32_16x16x32_bf16(a1, b, acc1_[nt], 0, 0, 0); \
            }                                                                   \
        }                                                                       \
    }

#define BNT 128

// GEMM1: h1 = relu(bn1(h @ W1 + b1))   [NPAD,128]x[128,256] -> bf16 [NPAD,256]
__global__ __launch_bounds__(256) void k_mm1(
    const ushort* __restrict__ A, const ushort* __restrict__ Wt,
    const float* __restrict__ bb, const float* __restrict__ g,
    const float* __restrict__ bt, const float* __restrict__ m,
    const float* __restrict__ vv, ushort* __restrict__ C) {
    __shared__ ushort s[BNT * 128];                  // 32 KB
    int tid = threadIdx.x;
    int bm = blockIdx.x >> 1, bn = blockIdx.x & 1;
    int ncol0 = bn * BNT;
    STAGE_WT(Wt, 128, 256);
    __syncthreads();
    int wid = tid >> 6, lane = tid & 63;
    int l15 = lane & 15, lq = lane >> 4;
    int r0 = bm * 128 + wid * 32 + l15;
    f32x4 acc0[8] = {}, acc1[8] = {};
    MM_LOOP(A, 128, 256, acc0, acc1);
#pragma unroll
    for (int nt = 0; nt < 8; ++nt) {
        int col = ncol0 + nt * 16 + l15;
        float sc = g[col] * rsqrtf(vv[col] + 1e-5f);
        float bo = (bb[col] - m[col]) * sc + bt[col];
        int rb = bm * 128 + wid * 32 + lq * 4;
#pragma unroll
        for (int r = 0; r < 4; ++r) {
            C[(size_t)(rb + r) * KDOUT + col] = f2bf(fmaxf(acc0[nt][r] * sc + bo, 0.f));
            C[(size_t)(rb + 16 + r) * KDOUT + col] = f2bf(fmaxf(acc1[nt][r] * sc + bo, 0.f));
        }
    }
}

// GEMM2 fused: out = relu( relu(bn2(h1 @ W2 + b2)) + x @ Wres )
__global__ __launch_bounds__(256) void k_mm2(
    const ushort* __restrict__ H1, const ushort* __restrict__ W2t,
    const ushort* __restrict__ X, const ushort* __restrict__ Wrt,
    const float* __restrict__ bb, const float* __restrict__ g,
    const float* __restrict__ bt, const float* __restrict__ m,
    const float* __restrict__ vv, float* __restrict__ OUT) {
    __shared__ ushort s[BNT * 256];                  // 64 KB
    int tid = threadIdx.x;
    int bm = blockIdx.x >> 1, bn = blockIdx.x & 1;
    int ncol0 = bn * BNT;
    int wid = tid >> 6, lane = tid & 63;
    int l15 = lane & 15, lq = lane >> 4;
    int r0 = bm * 128 + wid * 32 + l15;

    STAGE_WT(W2t, 256, 512);                         // phase 1: h1 @ W2
    __syncthreads();
    f32x4 acc0[8] = {}, acc1[8] = {};
    MM_LOOP(H1, 256, 512, acc0, acc1);

    __syncthreads();                                 // re-stage: Wres^T
    STAGE_WT(Wrt, 128, 256);
    __syncthreads();
    f32x4 acd0[8] = {}, acd1[8] = {};
    MM_LOOP(X, 128, 256, acd0, acd1);

#pragma unroll
    for (int nt = 0; nt < 8; ++nt) {
        int col = ncol0 + nt * 16 + l15;
        float sc = g[col] * rsqrtf(vv[col] + 1e-5f);
        float bo = (bb[col] - m[col]) * sc + bt[col];
        int rb = bm * 128 + wid * 32 + lq * 4;
#pragma unroll
        for (int r = 0; r < 4; ++r) {
            int row0 = rb + r, row1 = rb + 16 + r;
            float t0 = fmaxf(acc0[nt][r] * sc + bo, 0.f);
            float t1 = fmaxf(acc1[nt][r] * sc + bo, 0.f);
            if (row0 < NN) OUT[(size_t)row0 * KDOUT + col] = fmaxf(t0 + acd0[nt][r], 0.f);
            if (row1 < NN) OUT[(size_t)row1 * KDOUT + col] = fmaxf(t1 + acd1[nt][r], 0.f);
        }
    }
}

// ------------------------------------------------------------------- launch
extern "C" void kernel_launch(void* const* d_in, const int* in_sizes, int n_in,
                              void* d_out, int out_size, void* d_ws, size_t ws_size,
                              hipStream_t stream) {
    const float* x    = (const float*)d_in[0];
    const int*   ei   = (const int*)d_in[1];
    const float* eps  = (const float*)d_in[2];
    const float* W1   = (const float*)d_in[3];
    const float* b1   = (const float*)d_in[4];
    const float* g1   = (const float*)d_in[5];
    const float* bt1  = (const float*)d_in[6];
    const float* m1   = (const float*)d_in[7];
    const float* v1   = (const float*)d_in[8];
    const float* W2   = (const float*)d_in[9];
    const float* b2   = (const float*)d_in[10];
    const float* g2   = (const float*)d_in[11];
    const float* bt2  = (const float*)d_in[12];
    const float* m2   = (const float*)d_in[13];
    const float* v2   = (const float*)d_in[14];
    const float* Wres = (const float*)d_in[15];
    float* out = (float*)d_out;

    char* w = (char*)d_ws;
    ushort* xb  = (ushort*)w;                 w += (size_t)NPAD * KDIN * 2;   // 10.3 MB
    ushort* hb  = (ushort*)w;                 w += (size_t)NPAD * KDIN * 2;   // 10.3 MB
    ushort* h1b = (ushort*)w;                 w += (size_t)NPAD * KDOUT * 2;  // 20.5 MB
    ushort* w1t = (ushort*)w;                 w += 256 * 128 * 2;
    ushort* w2t = (ushort*)w;                 w += 256 * 256 * 2;
    ushort* wrt = (ushort*)w;                 w += 256 * 128 * 2;
    int* cur    = (int*)w;                    w += 256 * 4;                   // NB cursors
    unsigned int* recs = (unsigned int*)w;    w += (size_t)NB * CAP * 4;      // 3.86 MB

    // fused prep: x->bf16 (incl. zero pads), weight transposes, hb pads=0, cur=0
    k_prep<<<PREP_GRID, 256, 0, stream>>>(x, W1, W2, Wres, xb, w1t, cur, hb);
    // phase A: bin edges by dst>>8 with LDS staging (coalesced record writes)
    k_binA<<<NB, 256, 0, stream>>>(ei, cur, recs);
    // phase B: per-bucket LDS sort + register gather -> hb
    k_aggB<<<NB * 2, 256, 0, stream>>>(recs, cur, xb, eps, hb);

    const int grid = (NPAD / 128) * 2;        // 313 m-tiles x 2 n-tiles
    k_mm1<<<grid, 256, 0, stream>>>(hb, w1t, b1, g1, bt1, m1, v1, h1b);
    k_mm2<<<grid, 256, 0, stream>>>(h1b, w2t, xb, wrt, b2, g2, bt2, m2, v2, out);
}

// Round 6
// 104.643 us; speedup vs baseline: 12.2074x; 1.1887x over previous
//
#include <hip/hip_runtime.h>

#define NN 40000
#define NPAD 40064          // 313 * 128
#define EE 640000
#define KDIN 128
#define KDOUT 256

#define NB 157              // coarse buckets: dst >> 8
#define CAP 6144            // per-bucket record capacity (mean 4076, +32 sigma)
#define CAPH 4096           // per half-bucket capacity (mean 2038, +45 sigma)

typedef __attribute__((ext_vector_type(8))) short bf16x8;   // 8 bf16 = 4 VGPR
typedef __attribute__((ext_vector_type(4))) float f32x4;    // MFMA acc

static __device__ __forceinline__ unsigned short f2bf(float f) {
    union { float f; unsigned int u; } v; v.f = f;
    unsigned int r = (v.u + 0x7FFFu + ((v.u >> 16) & 1u)) >> 16;  // RNE
    return (unsigned short)r;
}
static __device__ __forceinline__ float bf2f(unsigned short h) {
    union { unsigned int u; float f; } v; v.u = ((unsigned int)h) << 16;
    return v.f;
}

// ------------------------------------------------------------------- prep
//   [0, 2504)      : x -> bf16 (NPAD rows; pad rows = 0)
//   [2504, 3016)   : W1/W2/Wres transpose+convert -> w1t|w2t|wrt (concat)
//   [3016, 3020)   : hb pad rows = 0
//   [3020, 3021)   : bucket cursors = 0
#define PREP_GRID 3021
__global__ __launch_bounds__(256) void k_prep(
    const float* __restrict__ x,
    const float* __restrict__ W1, const float* __restrict__ W2,
    const float* __restrict__ Wres,
    ushort* __restrict__ xb, ushort* __restrict__ wt_all,
    int* __restrict__ cur, ushort* __restrict__ hb) {
    int b = blockIdx.x, tid = threadIdx.x;
    if (b < 2504) {                                  // x convert, 8 elems/thread
        int i = b * 256 + tid;                       // elem8 index
        int row = i >> 4;
        uint4 o = {0, 0, 0, 0};
        if (row < NN) {
            const float4* xp = (const float4*)x + (size_t)i * 2;
            float4 a = xp[0], c = xp[1];
            o.x = (unsigned)f2bf(a.x) | ((unsigned)f2bf(a.y) << 16);
            o.y = (unsigned)f2bf(a.z) | ((unsigned)f2bf(a.w) << 16);
            o.z = (unsigned)f2bf(c.x) | ((unsigned)f2bf(c.y) << 16);
            o.w = (unsigned)f2bf(c.z) | ((unsigned)f2bf(c.w) << 16);
        }
        if (row < NPAD) *(uint4*)(xb + (size_t)i * 8) = o;
    } else if (b < 3016) {                           // weight transposes
        int j = (b - 2504) * 256 + tid;              // concat index
        if (j < 32768) {                             // w1t [256][128]
            int c = j >> 7, r = j & 127;
            wt_all[j] = f2bf(W1[r * KDOUT + c]);
        } else if (j < 98304) {                      // w2t [256][256]
            int j2 = j - 32768;
            int c = j2 >> 8, r = j2 & 255;
            wt_all[j] = f2bf(W2[r * KDOUT + c]);
        } else {                                     // wrt [256][128]
            int j3 = j - 98304;
            int c = j3 >> 7, r = j3 & 127;
            wt_all[j] = f2bf(Wres[r * KDOUT + c]);
        }
    } else if (b < 3020) {                           // hb pad rows = 0
        int idx = (b - 3016) * 256 + tid;            // 1024 uint4 = 16 KB
        ((uint4*)(hb + (size_t)NN * KDIN))[idx] = (uint4){0, 0, 0, 0};
    } else {                                         // bucket cursors = 0
        if (tid < NB) cur[tid] = 0;
    }
}

// ----------------------------------------------------- phase A: edge binning
// Each block: 4096 edges -> LDS bucket-sort by dst>>8 -> coalesced run writes.
// Record: (dst & 255) << 16 | src   (src < 65536)
__global__ __launch_bounds__(256) void k_binA(const int* __restrict__ ei,
                                              int* __restrict__ cur,
                                              unsigned int* __restrict__ recs) {
    __shared__ int cnt[160], lstart[160], lcur[160], gbase[160];
    __shared__ int sw[256];
    __shared__ unsigned int lrec[4096];
    __shared__ int laddr[4096];
    int tid = threadIdx.x;
    int e0 = blockIdx.x * 4096;
    int e1 = min(e0 + 4096, EE);
    int ns = e1 - e0;

    if (tid < NB) cnt[tid] = 0;
    __syncthreads();
    for (int s = tid; s < ns; s += 256)
        atomicAdd(&cnt[ei[EE + e0 + s] >> 8], 1);
    __syncthreads();
    // inclusive scan over 256 slots (cnt beyond NB treated as 0)
    sw[tid] = (tid < NB) ? cnt[tid] : 0;
    __syncthreads();
    for (int off = 1; off < 256; off <<= 1) {
        int add = (tid >= off) ? sw[tid - off] : 0;
        __syncthreads();
        sw[tid] += add;
        __syncthreads();
    }
    if (tid < NB) {
        int st = sw[tid] - cnt[tid];                 // block-local exclusive
        lstart[tid] = st;
        lcur[tid] = st;
        gbase[tid] = atomicAdd(&cur[tid], cnt[tid]); // reserve global run
    }
    __syncthreads();
    for (int s = tid; s < ns; s += 256) {
        int e = e0 + s;
        int src = ei[e];
        int dst = ei[EE + e];
        int b = dst >> 8;
        int p = atomicAdd(&lcur[b], 1);
        lrec[p] = ((unsigned int)(dst & 255) << 16) | (unsigned int)src;
        laddr[p] = b * CAP + gbase[b] + (p - lstart[b]);
    }
    __syncthreads();
    for (int s = tid; s < ns; s += 256)              // piecewise-contiguous
        recs[laddr[s]] = lrec[s];
}

// -------------------------------------------- phase B: aggregate per bucket
// Grid NB*8: blockIdx = b*8 + nh*4 + q  (nh: node-half of 128, q: dim-quarter
// of 32 dims). Each block filters its half's records, LDS counting-sorts by
// dst-low7, then register-gathers its dim quarter. 4-lane groups, 64 groups.
__global__ __launch_bounds__(256) void k_aggB(const unsigned int* __restrict__ recs,
                                              const int* __restrict__ cur,
                                              const ushort* __restrict__ xb,
                                              const float* __restrict__ eps,
                                              ushort* __restrict__ hb) {
    __shared__ ushort lsrc[CAPH];
    __shared__ int lcnt[128], lst[128], lcur[128];
    __shared__ int sw[256];
    int tid = threadIdx.x;
    int bi = blockIdx.x;
    int b = bi >> 3, nh = (bi >> 2) & 1, q = bi & 3;
    int cnt = cur[b];
    const unsigned int* rb = recs + (size_t)b * CAP;

    if (tid < 128) lcnt[tid] = 0;
    __syncthreads();
    for (int s = tid; s < cnt; s += 256) {
        int d = rb[s] >> 16;
        if ((d >> 7) == nh) atomicAdd(&lcnt[d & 127], 1);
    }
    __syncthreads();
    sw[tid] = (tid < 128) ? lcnt[tid] : 0;
    __syncthreads();
    for (int off = 1; off < 128; off <<= 1) {
        int add = (tid >= off) ? sw[tid - off] : 0;
        __syncthreads();
        sw[tid] += add;
        __syncthreads();
    }
    if (tid < 128) {
        int e = sw[tid] - lcnt[tid];
        lst[tid] = e;
        lcur[tid] = e;
    }
    __syncthreads();
    for (int s = tid; s < cnt; s += 256) {
        unsigned int r = rb[s];
        int d = r >> 16;
        if ((d >> 7) == nh) {
            int p = atomicAdd(&lcur[d & 127], 1);
            lsrc[p] = (ushort)(r & 0xffff);
        }
    }
    __syncthreads();

    int g = tid >> 2, lane = tid & 3;                // 64 groups x 4 lanes
    float s1 = 1.0f + eps[0];
    for (int d = g; d < 128; d += 64) {              // 2 iterations
        int node = b * 256 + nh * 128 + d;
        if (node >= NN) continue;
        int st = lst[d], en = st + lcnt[d];
        uint4 me = *((const uint4*)(xb + (size_t)node * KDIN) + q * 4 + lane);
        float a[8], a2[8];
        a[0] = bf2f((ushort)(me.x & 0xffff)) * s1; a[1] = bf2f((ushort)(me.x >> 16)) * s1;
        a[2] = bf2f((ushort)(me.y & 0xffff)) * s1; a[3] = bf2f((ushort)(me.y >> 16)) * s1;
        a[4] = bf2f((ushort)(me.z & 0xffff)) * s1; a[5] = bf2f((ushort)(me.z >> 16)) * s1;
        a[6] = bf2f((ushort)(me.w & 0xffff)) * s1; a[7] = bf2f((ushort)(me.w >> 16)) * s1;
#pragma unroll
        for (int i = 0; i < 8; ++i) a2[i] = 0.f;
        int e = st;
        for (; e + 1 < en; e += 2) {                 // 2 loads in flight
            int s0 = lsrc[e], sB = lsrc[e + 1];
            uint4 v0 = *((const uint4*)(xb + (size_t)s0 * KDIN) + q * 4 + lane);
            uint4 v1 = *((const uint4*)(xb + (size_t)sB * KDIN) + q * 4 + lane);
            a[0] += bf2f((ushort)(v0.x & 0xffff)); a[1] += bf2f((ushort)(v0.x >> 16));
            a[2] += bf2f((ushort)(v0.y & 0xffff)); a[3] += bf2f((ushort)(v0.y >> 16));
            a[4] += bf2f((ushort)(v0.z & 0xffff)); a[5] += bf2f((ushort)(v0.z >> 16));
            a[6] += bf2f((ushort)(v0.w & 0xffff)); a[7] += bf2f((ushort)(v0.w >> 16));
            a2[0] += bf2f((ushort)(v1.x & 0xffff)); a2[1] += bf2f((ushort)(v1.x >> 16));
            a2[2] += bf2f((ushort)(v1.y & 0xffff)); a2[3] += bf2f((ushort)(v1.y >> 16));
            a2[4] += bf2f((ushort)(v1.z & 0xffff)); a2[5] += bf2f((ushort)(v1.z >> 16));
            a2[6] += bf2f((ushort)(v1.w & 0xffff)); a2[7] += bf2f((ushort)(v1.w >> 16));
        }
        if (e < en) {
            int s0 = lsrc[e];
            uint4 v0 = *((const uint4*)(xb + (size_t)s0 * KDIN) + q * 4 + lane);
            a[0] += bf2f((ushort)(v0.x & 0xffff)); a[1] += bf2f((ushort)(v0.x >> 16));
            a[2] += bf2f((ushort)(v0.y & 0xffff)); a[3] += bf2f((ushort)(v0.y >> 16));
            a[4] += bf2f((ushort)(v0.z & 0xffff)); a[5] += bf2f((ushort)(v0.z >> 16));
            a[6] += bf2f((ushort)(v0.w & 0xffff)); a[7] += bf2f((ushort)(v0.w >> 16));
        }
#pragma unroll
        for (int i = 0; i < 8; ++i) a[i] += a2[i];
        uint4 o;
        o.x = (unsigned)f2bf(a[0]) | ((unsigned)f2bf(a[1]) << 16);
        o.y = (unsigned)f2bf(a[2]) | ((unsigned)f2bf(a[3]) << 16);
        o.z = (unsigned)f2bf(a[4]) | ((unsigned)f2bf(a[5]) << 16);
        o.w = (unsigned)f2bf(a[6]) | ((unsigned)f2bf(a[7]) << 16);
        *((uint4*)(hb + (size_t)node * KDIN) + q * 4 + lane) = o;
    }
}

// ------------------------------------------------------------ MFMA GEMMs
// Block: 256 threads = 4 waves. Tile BM=128 x BN=128. Wave w: rows w*32..+31.
// W^T column slice staged in LDS, XOR-swizzled: byte ^= (col&7)<<4.
// A-fragments loaded directly from global (L3-resident, read once per block).

#define STAGE_WT(Wt_, Kc_, K2_)                                                 \
    for (int id = tid; id < BNT * (K2_) / 16; id += 256) {                      \
        int c = id / ((K2_) / 16);                                              \
        int koff = (id % ((K2_) / 16)) * 16;                                    \
        uint4 v = *(const uint4*)((const char*)((Wt_) + (size_t)(ncol0 + c) * (Kc_)) + koff); \
        *(uint4*)((char*)s + c * (K2_) + (koff ^ ((c & 7) << 4))) = v;          \
    }

#define MM_LOOP(A_, Kc_, K2_, acc0_, acc1_)                                     \
    {                                                                           \
        const char* a0p = (const char*)((A_) + (size_t)r0 * (Kc_)) + lq * 16;   \
        const char* a1p = a0p + 16 * (Kc_) * 2;                                 \
        for (int k0 = 0; k0 < (Kc_); k0 += 32) {                                \
            bf16x8 a0 = *(const bf16x8*)(a0p + k0 * 2);                         \
            bf16x8 a1 = *(const bf16x8*)(a1p + k0 * 2);                         \
            int kb = (k0 + lq * 8) * 2;                                         \
            _Pragma("unroll")                                                   \
            for (int nt = 0; nt < 8; ++nt) {                                    \
                int c = nt * 16 + l15;                                          \
                bf16x8 b = *(const bf16x8*)((const char*)s + c * (K2_) + (kb ^ ((c & 7) << 4))); \
                acc0_[nt] = __builtin_amdgcn_mfma_f32_16x16x32_bf16(a0, b, acc0_[nt], 0, 0, 0); \
                acc1_[nt] = __builtin_amdgcn_mfma_f32_16x16x32_bf16(a1, b, acc1_[nt], 0, 0, 0); \
            }                                                                   \
        }                                                                       \
    }

#define BNT 128

// GEMM1: h1 = relu(bn1(h @ W1 + b1))   [NPAD,128]x[128,256] -> bf16 [NPAD,256]
__global__ __launch_bounds__(256) void k_mm1(
    const ushort* __restrict__ A, const ushort* __restrict__ Wt,
    const float* __restrict__ bb, const float* __restrict__ g,
    const float* __restrict__ bt, const float* __restrict__ m,
    const float* __restrict__ vv, ushort* __restrict__ C) {
    __shared__ ushort s[BNT * 128];                  // 32 KB
    int tid = threadIdx.x;
    int bm = blockIdx.x >> 1, bn = blockIdx.x & 1;
    int ncol0 = bn * BNT;
    STAGE_WT(Wt, 128, 256);
    __syncthreads();
    int wid = tid >> 6, lane = tid & 63;
    int l15 = lane & 15, lq = lane >> 4;
    int r0 = bm * 128 + wid * 32 + l15;
    f32x4 acc0[8] = {}, acc1[8] = {};
    MM_LOOP(A, 128, 256, acc0, acc1);
#pragma unroll
    for (int nt = 0; nt < 8; ++nt) {
        int col = ncol0 + nt * 16 + l15;
        float sc = g[col] * rsqrtf(vv[col] + 1e-5f);
        float bo = (bb[col] - m[col]) * sc + bt[col];
        int rb = bm * 128 + wid * 32 + lq * 4;
#pragma unroll
        for (int r = 0; r < 4; ++r) {
            C[(size_t)(rb + r) * KDOUT + col] = f2bf(fmaxf(acc0[nt][r] * sc + bo, 0.f));
            C[(size_t)(rb + 16 + r) * KDOUT + col] = f2bf(fmaxf(acc1[nt][r] * sc + bo, 0.f));
        }
    }
}

// GEMM2 fused: out = relu( relu(bn2(h1 @ W2 + b2)) + x @ Wres )
__global__ __launch_bounds__(256) void k_mm2(
    const ushort* __restrict__ H1, const ushort* __restrict__ W2t,
    const ushort* __restrict__ X, const ushort* __restrict__ Wrt,
    const float* __restrict__ bb, const float* __restrict__ g,
    const float* __restrict__ bt, const float* __restrict__ m,
    const float* __restrict__ vv, float* __restrict__ OUT) {
    __shared__ ushort s[BNT * 256];                  // 64 KB
    int tid = threadIdx.x;
    int bm = blockIdx.x >> 1, bn = blockIdx.x & 1;
    int ncol0 = bn * BNT;
    int wid = tid >> 6, lane = tid & 63;
    int l15 = lane & 15, lq = lane >> 4;
    int r0 = bm * 128 + wid * 32 + l15;

    STAGE_WT(W2t, 256, 512);                         // phase 1: h1 @ W2
    __syncthreads();
    f32x4 acc0[8] = {}, acc1[8] = {};
    MM_LOOP(H1, 256, 512, acc0, acc1);

    __syncthreads();                                 // re-stage: Wres^T
    STAGE_WT(Wrt, 128, 256);
    __syncthreads();
    f32x4 acd0[8] = {}, acd1[8] = {};
    MM_LOOP(X, 128, 256, acd0, acd1);

#pragma unroll
    for (int nt = 0; nt < 8; ++nt) {
        int col = ncol0 + nt * 16 + l15;
        float sc = g[col] * rsqrtf(vv[col] + 1e-5f);
        float bo = (bb[col] - m[col]) * sc + bt[col];
        int rb = bm * 128 + wid * 32 + lq * 4;
#pragma unroll
        for (int r = 0; r < 4; ++r) {
            int row0 = rb + r, row1 = rb + 16 + r;
            float t0 = fmaxf(acc0[nt][r] * sc + bo, 0.f);
            float t1 = fmaxf(acc1[nt][r] * sc + bo, 0.f);
            if (row0 < NN) OUT[(size_t)row0 * KDOUT + col] = fmaxf(t0 + acd0[nt][r], 0.f);
            if (row1 < NN) OUT[(size_t)row1 * KDOUT + col] = fmaxf(t1 + acd1[nt][r], 0.f);
        }
    }
}

// ------------------------------------------------------------------- launch
extern "C" void kernel_launch(void* const* d_in, const int* in_sizes, int n_in,
                              void* d_out, int out_size, void* d_ws, size_t ws_size,
                              hipStream_t stream) {
    const float* x    = (const float*)d_in[0];
    const int*   ei   = (const int*)d_in[1];
    const float* eps  = (const float*)d_in[2];
    const float* W1   = (const float*)d_in[3];
    const float* b1   = (const float*)d_in[4];
    const float* g1   = (const float*)d_in[5];
    const float* bt1  = (const float*)d_in[6];
    const float* m1   = (const float*)d_in[7];
    const float* v1   = (const float*)d_in[8];
    const float* W2   = (const float*)d_in[9];
    const float* b2   = (const float*)d_in[10];
    const float* g2   = (const float*)d_in[11];
    const float* bt2  = (const float*)d_in[12];
    const float* m2   = (const float*)d_in[13];
    const float* v2   = (const float*)d_in[14];
    const float* Wres = (const float*)d_in[15];
    float* out = (float*)d_out;

    char* w = (char*)d_ws;
    ushort* xb  = (ushort*)w;                 w += (size_t)NPAD * KDIN * 2;   // 10.3 MB
    ushort* hb  = (ushort*)w;                 w += (size_t)NPAD * KDIN * 2;   // 10.3 MB
    ushort* h1b = (ushort*)w;                 w += (size_t)NPAD * KDOUT * 2;  // 20.5 MB
    ushort* w1t = (ushort*)w;                 w += 256 * 128 * 2;
    ushort* w2t = (ushort*)w;                 w += 256 * 256 * 2;
    ushort* wrt = (ushort*)w;                 w += 256 * 128 * 2;
    int* cur    = (int*)w;                    w += 256 * 4;                   // NB cursors
    unsigned int* recs = (unsigned int*)w;    w += (size_t)NB * CAP * 4;      // 3.86 MB

    // fused prep: x->bf16 (incl. zero pads), weight transposes, hb pads=0, cur=0
    k_prep<<<PREP_GRID, 256, 0, stream>>>(x, W1, W2, Wres, xb, w1t, cur, hb);
    // phase A: bin edges by dst>>8 with LDS staging (coalesced record writes)
    k_binA<<<NB, 256, 0, stream>>>(ei, cur, recs);
    // phase B: per (bucket, node-half, dim-quarter) LDS sort + register gather
    k_aggB<<<NB * 8, 256, 0, stream>>>(recs, cur, xb, eps, hb);

    const int grid = (NPAD / 128) * 2;        // 313 m-tiles x 2 n-tiles
    k_mm1<<<grid, 256, 0, stream>>>(hb, w1t, b1, g1, bt1, m1, v1, h1b);
    k_mm2<<<grid, 256, 0, stream>>>(h1b, w2t, xb, wrt, b2, g2, bt2, m2, v2, out);
}